// Round 1
// baseline (2064.152 us; speedup 1.0000x reference)
//
#include <hip/hip_runtime.h>
#include <math.h>

#define Bn 4096
#define Tn 512
#define Vn 57
#define En 20
#define Hn 128
#define On 18
#define ROWS 16          // rows per block
#define NTHR 512         // 8 waves
#define NBLK (Bn / ROWS) // 256 blocks -> 1 per CU
#define HPAD 20          // padded row stride (floats) for transposed h: 16B-aligned float4, odd-ish banking

__device__ __forceinline__ float fast_tanh(float x) {
    // tanh(x) = 1 - 2/(exp(2x)+1); safe at +-inf (exp->inf gives 1, exp->0 gives -1)
    float e = __expf(2.0f * x);
    return 1.0f - __fdividef(2.0f, e + 1.0f);
}

__launch_bounds__(NTHR)
__global__ void rnn_fused_kernel(const int* __restrict__ x,
                                 const int* __restrict__ xlen,
                                 const float* __restrict__ emb,
                                 const float* __restrict__ W_ih,
                                 const float* __restrict__ W_hh,
                                 const float* __restrict__ b_ih,
                                 const float* __restrict__ b_hh,
                                 const float* __restrict__ W_out,
                                 const float* __restrict__ b_out,
                                 float* __restrict__ out)
{
    // LDS budget: 66048 + 29184 + 20480 + ~1220 = ~116.9 KB  (< 160 KB, 1 block/CU)
    __shared__ __align__(16) float sWT[Hn * (Hn + 1)];   // W_hh^T: sWT[k*(129)+j] = W_hh[j][k]
    __shared__ __align__(16) float sProj[Vn * Hn];       // proj[c][j] = emb[c]@W_ih[j] + b_ih[j] + b_hh[j]
    __shared__ __align__(16) float sH[2][Hn * HPAD];     // h transposed: sH[buf][k*HPAD + r]
    __shared__ float sLogit[ROWS][On];
    __shared__ float sMLS[ROWS];

    const int tid  = threadIdx.x;
    const int blk  = blockIdx.x;
    const int row0 = blk * ROWS;

    // ---- stage W_hh transposed (global read coalesced; LDS write stride 129 -> conflict-free)
    for (int idx = tid; idx < Hn * Hn; idx += NTHR) {
        int j = idx >> 7, k = idx & 127;
        sWT[k * (Hn + 1) + j] = W_hh[idx];
    }
    // ---- build the 57-entry projection table (replaces the whole B*T*E*H einsum)
    for (int idx = tid; idx < Vn * Hn; idx += NTHR) {
        int c = idx >> 7, j = idx & 127;
        float acc = b_ih[j] + b_hh[j];
        #pragma unroll
        for (int e = 0; e < En; ++e)
            acc += emb[c * En + e] * W_ih[j * En + e];
        sProj[idx] = acc;
    }
    // ---- zero h buffers (h0 = 0)
    for (int idx = tid; idx < 2 * Hn * HPAD; idx += NTHR)
        (&sH[0][0])[idx] = 0.0f;
    __syncthreads();

    // thread mapping: j = tid & 127 (output column), rg = tid >> 7 -> rows rg*4 .. rg*4+3
    const int j  = tid & 127;
    const int rg = tid >> 7;
    const int r4 = rg * 4;

    int len_i[4];
    #pragma unroll
    for (int i = 0; i < 4; ++i) len_i[i] = xlen[row0 + r4 + i];
    const int Lmax = xlen[row0];  // lengths sorted descending -> block-max trip count

    float hreg[4] = {0.f, 0.f, 0.f, 0.f};

    int c_cur[4];
    #pragma unroll
    for (int i = 0; i < 4; ++i) c_cur[i] = x[(row0 + r4 + i) * Tn + 0];

    for (int t = 0; t < Lmax; ++t) {
        const float* hb = sH[t & 1];
        float*       hn = sH[(t & 1) ^ 1];

        // prefetch next step's vocab ids (latency hidden under k-loop)
        int c_nxt[4] = {0, 0, 0, 0};
        if (t + 1 < Lmax) {
            #pragma unroll
            for (int i = 0; i < 4; ++i) c_nxt[i] = x[(row0 + r4 + i) * Tn + t + 1];
        }

        float acc0 = sProj[c_cur[0] * Hn + j];
        float acc1 = sProj[c_cur[1] * Hn + j];
        float acc2 = sProj[c_cur[2] * Hn + j];
        float acc3 = sProj[c_cur[3] * Hn + j];

        #pragma unroll 16
        for (int k = 0; k < Hn; ++k) {
            float  w  = sWT[k * (Hn + 1) + j];                     // conflict-free b32
            float4 hv = *(const float4*)(&hb[k * HPAD + r4]);      // wave-broadcast b128 (4 rows)
            acc0 = fmaf(w, hv.x, acc0);
            acc1 = fmaf(w, hv.y, acc1);
            acc2 = fmaf(w, hv.z, acc2);
            acc3 = fmaf(w, hv.w, acc3);
        }

        // tanh + per-row packed-length mask (keep old h once past len)
        float h0 = fast_tanh(acc0);
        float h1 = fast_tanh(acc1);
        float h2 = fast_tanh(acc2);
        float h3 = fast_tanh(acc3);
        hreg[0] = (t < len_i[0]) ? h0 : hreg[0];
        hreg[1] = (t < len_i[1]) ? h1 : hreg[1];
        hreg[2] = (t < len_i[2]) ? h2 : hreg[2];
        hreg[3] = (t < len_i[3]) ? h3 : hreg[3];

        *(float4*)(&hn[j * HPAD + r4]) = make_float4(hreg[0], hreg[1], hreg[2], hreg[3]);

        #pragma unroll
        for (int i = 0; i < 4; ++i) c_cur[i] = c_nxt[i];

        __syncthreads();   // h double-buffered -> single barrier per step
    }

    // ---- epilogue: logits = relu(h) @ W_out^T + b_out, then log_softmax
    const float* hf = sH[Lmax & 1];

    for (int it = tid; it < ROWS * On; it += NTHR) {
        int r = it / On, c = it % On;
        float acc = b_out[c];
        for (int k = 0; k < Hn; ++k) {
            float hv = hf[k * HPAD + r];
            hv = hv > 0.0f ? hv : 0.0f;
            acc = fmaf(hv, W_out[c * Hn + k], acc);
        }
        sLogit[r][c] = acc;
    }
    __syncthreads();

    if (tid < ROWS) {
        float m = -INFINITY;
        #pragma unroll
        for (int c = 0; c < On; ++c) m = fmaxf(m, sLogit[tid][c]);
        float s = 0.0f;
        #pragma unroll
        for (int c = 0; c < On; ++c) s += __expf(sLogit[tid][c] - m);
        sMLS[tid] = m + __logf(s);
    }
    __syncthreads();

    for (int it = tid; it < ROWS * On; it += NTHR) {
        int r = it / On, c = it % On;
        out[(row0 + r) * On + c] = sLogit[r][c] - sMLS[r];
    }
}

extern "C" void kernel_launch(void* const* d_in, const int* in_sizes, int n_in,
                              void* d_out, int out_size, void* d_ws, size_t ws_size,
                              hipStream_t stream) {
    const int*   x     = (const int*)d_in[0];
    const int*   xlen  = (const int*)d_in[1];
    const float* emb   = (const float*)d_in[2];
    const float* W_ih  = (const float*)d_in[3];
    const float* W_hh  = (const float*)d_in[4];
    const float* b_ih  = (const float*)d_in[5];
    const float* b_hh  = (const float*)d_in[6];
    const float* W_out = (const float*)d_in[7];
    const float* b_out = (const float*)d_in[8];
    float*       out   = (float*)d_out;

    rnn_fused_kernel<<<NBLK, NTHR, 0, stream>>>(x, xlen, emb, W_ih, W_hh,
                                                b_ih, b_hh, W_out, b_out, out);
}

// Round 2
// 1463.042 us; speedup vs baseline: 1.4109x; 1.4109x over previous
//
#include <hip/hip_runtime.h>
#include <math.h>

#define Bn 4096
#define Tn 512
#define Vn 57
#define En 20
#define Hn 128
#define On 18
#define ROWS 16          // rows per block
#define NTHR 512         // 8 waves
#define NBLK (Bn / ROWS) // 256 blocks -> 1 per CU
#define HPAD 20          // padded row stride (floats) for transposed h (16B-aligned float4)

__device__ __forceinline__ float fast_tanh(float x) {
    float e = __expf(2.0f * x);
    return 1.0f - __fdividef(2.0f, e + 1.0f);
}

__launch_bounds__(NTHR)
__global__ void rnn_fused_kernel(const int* __restrict__ x,
                                 const int* __restrict__ xlen,
                                 const float* __restrict__ emb,
                                 const float* __restrict__ W_ih,
                                 const float* __restrict__ W_hh,
                                 const float* __restrict__ b_ih,
                                 const float* __restrict__ b_hh,
                                 const float* __restrict__ W_out,
                                 const float* __restrict__ b_out,
                                 float* __restrict__ out)
{
    // LDS: sProj 29184 + sH 20480 + small = ~50 KB (1 block/CU, 512 thr)
    __shared__ __align__(16) float sProj[Vn * Hn];       // proj[c][j] = emb[c]@W_ih[j] + b_ih[j] + b_hh[j]
    __shared__ __align__(16) float sH[2][Hn * HPAD];     // h transposed: sH[buf][k*HPAD + r]
    __shared__ float sLogit[ROWS][On];
    __shared__ float sMLS[ROWS];

    const int tid  = threadIdx.x;
    const int blk  = blockIdx.x;
    const int row0 = blk * ROWS;

    // thread mapping: j = tid & 127 (output column), rg = tid >> 7 -> rows rg*4 .. rg*4+3
    const int j  = tid & 127;
    const int rg = tid >> 7;
    const int r4 = rg * 4;

    // ---- W_hh row j register-resident: w[k] = W_hh[j][k]  (128 VGPRs, loaded once,
    //      amortized over ~482 steps; kills ALL weight LDS reads in the k-loop)
    float w[Hn];
    #pragma unroll
    for (int kq = 0; kq < Hn / 4; ++kq)
        *(float4*)&w[kq * 4] = *(const float4*)&W_hh[j * Hn + kq * 4];

    // ---- build the 57-entry projection table (replaces the whole B*T*E*H einsum)
    for (int idx = tid; idx < Vn * Hn; idx += NTHR) {
        int c = idx >> 7, jj = idx & 127;
        float acc = b_ih[jj] + b_hh[jj];
        #pragma unroll
        for (int e = 0; e < En; ++e)
            acc += emb[c * En + e] * W_ih[jj * En + e];
        sProj[idx] = acc;
    }
    // ---- zero h buffers (h0 = 0)
    for (int idx = tid; idx < 2 * Hn * HPAD; idx += NTHR)
        (&sH[0][0])[idx] = 0.0f;
    __syncthreads();

    int len_i[4];
    #pragma unroll
    for (int i = 0; i < 4; ++i) len_i[i] = xlen[row0 + r4 + i];
    const int Lmax = xlen[row0];  // lengths sorted descending -> block-max trip count

    float hreg[4] = {0.f, 0.f, 0.f, 0.f};

    int c_cur[4];
    #pragma unroll
    for (int i = 0; i < 4; ++i) c_cur[i] = x[(row0 + r4 + i) * Tn + 0];

    for (int t = 0; t < Lmax; ++t) {
        const float* hb = sH[t & 1];
        float*       hn = sH[(t & 1) ^ 1];

        // prefetch next step's vocab ids (latency hidden under k-loop)
        int c_nxt[4] = {0, 0, 0, 0};
        if (t + 1 < Lmax) {
            #pragma unroll
            for (int i = 0; i < 4; ++i) c_nxt[i] = x[(row0 + r4 + i) * Tn + t + 1];
        }

        float acc0 = sProj[c_cur[0] * Hn + j];
        float acc1 = sProj[c_cur[1] * Hn + j];
        float acc2 = sProj[c_cur[2] * Hn + j];
        float acc3 = sProj[c_cur[3] * Hn + j];

        // inner product: 1 broadcast ds_read_b128 + 4 FMA per k (weights from VGPRs)
        #pragma unroll
        for (int k = 0; k < Hn; ++k) {
            float4 hv = *(const float4*)(&hb[k * HPAD + r4]);  // wave-broadcast (same addr all lanes)
            acc0 = fmaf(w[k], hv.x, acc0);
            acc1 = fmaf(w[k], hv.y, acc1);
            acc2 = fmaf(w[k], hv.z, acc2);
            acc3 = fmaf(w[k], hv.w, acc3);
        }

        // tanh + per-row packed-length mask (keep old h once past len)
        float h0 = fast_tanh(acc0);
        float h1 = fast_tanh(acc1);
        float h2 = fast_tanh(acc2);
        float h3 = fast_tanh(acc3);
        hreg[0] = (t < len_i[0]) ? h0 : hreg[0];
        hreg[1] = (t < len_i[1]) ? h1 : hreg[1];
        hreg[2] = (t < len_i[2]) ? h2 : hreg[2];
        hreg[3] = (t < len_i[3]) ? h3 : hreg[3];

        *(float4*)(&hn[j * HPAD + r4]) = make_float4(hreg[0], hreg[1], hreg[2], hreg[3]);

        #pragma unroll
        for (int i = 0; i < 4; ++i) c_cur[i] = c_nxt[i];

        __syncthreads();   // h double-buffered -> single barrier per step
    }

    // ---- epilogue: logits = relu(h) @ W_out^T + b_out, then log_softmax
    const float* hf = sH[Lmax & 1];

    for (int it = tid; it < ROWS * On; it += NTHR) {
        int r = it / On, c = it % On;
        float acc = b_out[c];
        for (int k = 0; k < Hn; ++k) {
            float hv = hf[k * HPAD + r];
            hv = hv > 0.0f ? hv : 0.0f;
            acc = fmaf(hv, W_out[c * Hn + k], acc);
        }
        sLogit[r][c] = acc;
    }
    __syncthreads();

    if (tid < ROWS) {
        float m = -INFINITY;
        #pragma unroll
        for (int c = 0; c < On; ++c) m = fmaxf(m, sLogit[tid][c]);
        float s = 0.0f;
        #pragma unroll
        for (int c = 0; c < On; ++c) s += __expf(sLogit[tid][c] - m);
        sMLS[tid] = m + __logf(s);
    }
    __syncthreads();

    for (int it = tid; it < ROWS * On; it += NTHR) {
        int r = it / On, c = it % On;
        out[(row0 + r) * On + c] = sLogit[r][c] - sMLS[r];
    }
}

extern "C" void kernel_launch(void* const* d_in, const int* in_sizes, int n_in,
                              void* d_out, int out_size, void* d_ws, size_t ws_size,
                              hipStream_t stream) {
    const int*   x     = (const int*)d_in[0];
    const int*   xlen  = (const int*)d_in[1];
    const float* emb   = (const float*)d_in[2];
    const float* W_ih  = (const float*)d_in[3];
    const float* W_hh  = (const float*)d_in[4];
    const float* b_ih  = (const float*)d_in[5];
    const float* b_hh  = (const float*)d_in[6];
    const float* W_out = (const float*)d_in[7];
    const float* b_out = (const float*)d_in[8];
    float*       out   = (float*)d_out;

    rnn_fused_kernel<<<NBLK, NTHR, 0, stream>>>(x, xlen, emb, W_ih, W_hh,
                                                b_ih, b_hh, W_out, b_out, out);
}

// Round 3
// 379.113 us; speedup vs baseline: 5.4447x; 3.8591x over previous
//
#include <hip/hip_runtime.h>
#include <math.h>

#define Bn 4096
#define Tn 512
#define Vn 57
#define En 20
#define Hn 128
#define On 18
#define ROWS 16          // rows per block (= MFMA M)
#define NTHR 512         // 8 waves = 8 N-tiles of 16 cols
#define NBLK (Bn / ROWS) // 256 blocks -> 1 per CU
#define PSTR 132         // proj row stride (floats): breaks c*128 bank aliasing
#define HSTR 136         // h row stride (fp16): 272B, 16B-aligned, bank-spread for A-frag b128
#define XSTR 513         // staged x row stride (ints): conflict-free id reads

typedef _Float16 half8  __attribute__((ext_vector_type(8)));
typedef float    floatx4 __attribute__((ext_vector_type(4)));

__device__ __forceinline__ float fast_tanh(float x) {
    float e = __expf(2.0f * x);
    return 1.0f - __fdividef(2.0f, e + 1.0f);
}

__launch_bounds__(NTHR)
__global__ void rnn_mfma_kernel(const int* __restrict__ x,
                                const int* __restrict__ xlen,
                                const float* __restrict__ emb,
                                const float* __restrict__ W_ih,
                                const float* __restrict__ W_hh,
                                const float* __restrict__ b_ih,
                                const float* __restrict__ b_hh,
                                const float* __restrict__ W_out,
                                const float* __restrict__ b_out,
                                float* __restrict__ out)
{
    // LDS: proj 29.4KB + sHa 8.5KB + sHf 8.5KB + sX 32.1KB + misc ~1.3KB = ~80KB (1 blk/CU)
    __shared__ __align__(16) float    sProj[Vn * PSTR];      // proj[c][j] (C-operand of MFMA)
    __shared__ __align__(16) _Float16 sHa[2][ROWS][HSTR];    // h state, fp16, double-buffered
    __shared__ __align__(16) float    sHf[ROWS][HSTR];       // final h (fp32) for epilogue
    __shared__ int sX[ROWS * XSTR];                          // staged vocab ids
    __shared__ float sLogit[ROWS][On];
    __shared__ float sMLS[ROWS];

    const int tid  = threadIdx.x;
    const int blk  = blockIdx.x;
    const int row0 = blk * ROWS;

    const int wave = tid >> 6;
    const int lane = tid & 63;
    const int n    = lane & 15;        // MFMA M/N lane index
    const int q    = lane >> 4;        // quad 0..3
    const int jg   = wave * 16 + n;    // this lane's output column j (N dim)

    // ---- B fragments: B[k][n] = W_hh[jg][k], fp16 hi + 2048-scaled lo (static, 32 VGPRs)
    half8 Bh[4], Bl[4];
    #pragma unroll
    for (int kc = 0; kc < 4; ++kc) {
        const float* wp = &W_hh[jg * Hn + kc * 32 + q * 8];
        float4 w0 = *(const float4*)wp;
        float4 w1 = *(const float4*)(wp + 4);
        float wv[8] = {w0.x, w0.y, w0.z, w0.w, w1.x, w1.y, w1.z, w1.w};
        #pragma unroll
        for (int i = 0; i < 8; ++i) {
            _Float16 hi = (_Float16)wv[i];
            Bh[kc][i] = hi;
            Bl[kc][i] = (_Float16)((wv[i] - (float)hi) * 2048.0f); // stays fp16-normal
        }
    }

    // ---- proj table: proj[c][j] = emb[c]@W_ih[j] + b_ih[j] + b_hh[j]  (57 entries)
    for (int idx = tid; idx < Vn * Hn; idx += NTHR) {
        int c = idx >> 7, jj = idx & 127;
        float acc = b_ih[jj] + b_hh[jj];
        #pragma unroll
        for (int e = 0; e < En; ++e)
            acc += emb[c * En + e] * W_ih[jj * En + e];
        sProj[c * PSTR + jj] = acc;
    }
    // ---- stage this block's vocab ids (kills ALL per-step global traffic)
    for (int idx = tid; idx < ROWS * Tn; idx += NTHR) {
        int r = idx >> 9, t = idx & 511;
        sX[r * XSTR + t] = x[row0 * Tn + idx];   // coalesced global read
    }
    // ---- zero h state (h0 = 0)
    for (int idx = tid; idx < 2 * ROWS * HSTR; idx += NTHR)
        ((_Float16*)sHa)[idx] = (_Float16)0.0f;
    __syncthreads();

    int len_i[4];
    #pragma unroll
    for (int i = 0; i < 4; ++i) len_i[i] = xlen[row0 + 4 * q + i];
    const int Lmax = xlen[row0];   // lengths sorted descending

    float hreg[4] = {0.f, 0.f, 0.f, 0.f};

    for (int t = 0; t < Lmax; ++t) {
        const _Float16* hb = &sHa[t & 1][0][0];
        _Float16*       hn = &sHa[(t & 1) ^ 1][0][0];

        // C-operand init: acc_h = proj[id][jg] (the input projection, added for free)
        floatx4 acch, accl;
        #pragma unroll
        for (int i = 0; i < 4; ++i) {
            int c = sX[(4 * q + i) * XSTR + t];
            acch[i] = sProj[c * PSTR + jg];
            accl[i] = 0.0f;
        }

        // h[16x128] @ W_hh^T -> this wave's 16-col tile; A from LDS, B static in VGPRs
        #pragma unroll
        for (int kc = 0; kc < 4; ++kc) {
            half8 a = *(const half8*)&hb[n * HSTR + kc * 32 + q * 8]; // A[m=n][k=kc*32+q*8..+7]
            acch = __builtin_amdgcn_mfma_f32_16x16x32_f16(a, Bh[kc], acch, 0, 0, 0);
            accl = __builtin_amdgcn_mfma_f32_16x16x32_f16(a, Bl[kc], accl, 0, 0, 0);
        }

        // C layout: lane holds rows 4q+{0..3}, col jg. tanh + packed-length mask + store fp16
        #pragma unroll
        for (int i = 0; i < 4; ++i) {
            float hv = fast_tanh(acch[i] + accl[i] * (1.0f / 2048.0f));
            hreg[i] = (t < len_i[i]) ? hv : hreg[i];
            hn[(4 * q + i) * HSTR + jg] = (_Float16)hreg[i];
        }
        __syncthreads();   // double-buffered h -> one barrier per step
    }

    // ---- publish final fp32 h for the epilogue
    #pragma unroll
    for (int i = 0; i < 4; ++i)
        sHf[4 * q + i][jg] = hreg[i];
    __syncthreads();

    // ---- epilogue: logits = relu(h) @ W_out^T + b_out, then log_softmax
    for (int it = tid; it < ROWS * On; it += NTHR) {
        int r = it / On, c = it % On;
        float acc = b_out[c];
        for (int k = 0; k < Hn; ++k) {
            float hv = sHf[r][k];
            hv = hv > 0.0f ? hv : 0.0f;
            acc = fmaf(hv, W_out[c * Hn + k], acc);
        }
        sLogit[r][c] = acc;
    }
    __syncthreads();

    if (tid < ROWS) {
        float m = -INFINITY;
        #pragma unroll
        for (int c = 0; c < On; ++c) m = fmaxf(m, sLogit[tid][c]);
        float s = 0.0f;
        #pragma unroll
        for (int c = 0; c < On; ++c) s += __expf(sLogit[tid][c] - m);
        sMLS[tid] = m + __logf(s);
    }
    __syncthreads();

    for (int it = tid; it < ROWS * On; it += NTHR) {
        int r = it / On, c = it % On;
        out[(row0 + r) * On + c] = sLogit[r][c] - sMLS[r];
    }
}

extern "C" void kernel_launch(void* const* d_in, const int* in_sizes, int n_in,
                              void* d_out, int out_size, void* d_ws, size_t ws_size,
                              hipStream_t stream) {
    const int*   x     = (const int*)d_in[0];
    const int*   xlen  = (const int*)d_in[1];
    const float* emb   = (const float*)d_in[2];
    const float* W_ih  = (const float*)d_in[3];
    const float* W_hh  = (const float*)d_in[4];
    const float* b_ih  = (const float*)d_in[5];
    const float* b_hh  = (const float*)d_in[6];
    const float* W_out = (const float*)d_in[7];
    const float* b_out = (const float*)d_in[8];
    float*       out   = (float*)d_out;

    rnn_mfma_kernel<<<NBLK, NTHR, 0, stream>>>(x, xlen, emb, W_ih, W_hh,
                                               b_ih, b_hh, W_out, b_out, out);
}

// Round 4
// 325.494 us; speedup vs baseline: 6.3416x; 1.1647x over previous
//
#include <hip/hip_runtime.h>
#include <math.h>

#define Bn 4096
#define Tn 512
#define Vn 57
#define En 20
#define Hn 128
#define On 18
#define ROWS 16          // rows per block (= MFMA N now: batch dim)
#define NTHR 512         // 8 waves, one 16-col tile of h_new each
#define NBLK (Bn / ROWS) // 256 blocks -> 1 per CU (LDS ~81.5KB keeps it that way)
#define PSTR 132         // proj row stride (floats)
#define HSTR 136         // h row stride (fp16): 272B rows, 16B-aligned b128 reads
#define XSTR 513         // staged x row stride (ints): 513%32==1 -> conflict-free

typedef _Float16 half8  __attribute__((ext_vector_type(8)));
typedef _Float16 half4  __attribute__((ext_vector_type(4)));
typedef float    floatx4 __attribute__((ext_vector_type(4)));

__device__ __forceinline__ float fast_tanh(float x) {
    float e = __expf(2.0f * x);
    return 1.0f - __fdividef(2.0f, e + 1.0f);
}

__launch_bounds__(NTHR)
__global__ void rnn_mfma_kernel(const int* __restrict__ x,
                                const int* __restrict__ xlen,
                                const float* __restrict__ emb,
                                const float* __restrict__ W_ih,
                                const float* __restrict__ W_hh,
                                const float* __restrict__ b_ih,
                                const float* __restrict__ b_hh,
                                const float* __restrict__ W_out,
                                const float* __restrict__ b_out,
                                float* __restrict__ out)
{
    __shared__ __align__(16) float    sProj[Vn * PSTR];   // proj[c][j]
    __shared__ __align__(16) _Float16 sHa[2][ROWS][HSTR]; // h[batch][col] fp16, dbuf
    __shared__ __align__(16) float    sHf[ROWS][HSTR];    // final fp32 h
    __shared__ int sX[ROWS * XSTR];                       // sX[batch][t]
    __shared__ float sLogit[ROWS][On];
    __shared__ float sMLS[ROWS];

    const int tid  = threadIdx.x;
    const int blk  = blockIdx.x;
    const int row0 = blk * ROWS;

    const int wave = tid >> 6;
    const int lane = tid & 63;
    const int n    = lane & 15;      // MFMA lane index: batch row (B/C) AND W-row-within-tile (A)
    const int q    = lane >> 4;      // quad
    const int jg0  = wave * 16;      // this wave's 16 h_new columns [jg0, jg0+16)

    // ---- A-operand: W_hh rows jg0+n, fp16 hi + 2048*lo residual, static in 32 VGPRs
    // A[m=lane&15][k=q*8+j+32kc] = W_hh[jg0+m][k]
    half8 Ah[4], Al[4];
    #pragma unroll
    for (int kc = 0; kc < 4; ++kc) {
        const float* wp = &W_hh[(jg0 + n) * Hn + kc * 32 + q * 8];
        float4 w0 = *(const float4*)wp;
        float4 w1 = *(const float4*)(wp + 4);
        float wv[8] = {w0.x, w0.y, w0.z, w0.w, w1.x, w1.y, w1.z, w1.w};
        #pragma unroll
        for (int i = 0; i < 8; ++i) {
            _Float16 hi = (_Float16)wv[i];
            Ah[kc][i] = hi;
            Al[kc][i] = (_Float16)((wv[i] - (float)hi) * 2048.0f);
        }
    }

    // ---- proj table: proj[c][j] = emb[c]@W_ih[j] + b_ih[j] + b_hh[j]
    for (int idx = tid; idx < Vn * Hn; idx += NTHR) {
        int c = idx >> 7, jj = idx & 127;
        float acc = b_ih[jj] + b_hh[jj];
        #pragma unroll
        for (int e = 0; e < En; ++e)
            acc += emb[c * En + e] * W_ih[jj * En + e];
        sProj[c * PSTR + jj] = acc;
    }
    // ---- stage vocab ids: sX[r][t]
    for (int idx = tid; idx < ROWS * Tn; idx += NTHR) {
        int r = idx >> 9, t = idx & 511;
        sX[r * XSTR + t] = x[row0 * Tn + idx];
    }
    // ---- zero h state
    for (int idx = tid; idx < 2 * ROWS * HSTR; idx += NTHR)
        ((_Float16*)sHa)[idx] = (_Float16)0.0f;
    __syncthreads();

    const int len_n = xlen[row0 + n];  // this lane's batch row length
    const int Lmax  = xlen[row0];      // sorted descending -> block trip count

    float hreg[4] = {0.f, 0.f, 0.f, 0.f};

    // ---- prefetch step-0 C-init: one b32 + one b128 per lane
    int id_cur = sX[n * XSTR + 0];
    float4 prj = *(const float4*)&sProj[id_cur * PSTR + jg0 + 4 * q];

    for (int t = 0; t < Lmax; ++t) {
        const _Float16* hb = &sHa[t & 1][0][0];
        _Float16*       hn = &sHa[(t & 1) ^ 1][0][0];

        // B-operand: B[k][n] = h[batch n][k] -- 4 contiguous b128 reads
        half8 b[4];
        #pragma unroll
        for (int kc = 0; kc < 4; ++kc)
            b[kc] = *(const half8*)&hb[n * HSTR + kc * 32 + q * 8];

        // prefetch t+1's C-init (sX/sProj are static -> off the critical path)
        int tn = (t + 1 < Lmax) ? t + 1 : Lmax - 1;
        int id2 = sX[n * XSTR + tn];
        float4 prj2 = *(const float4*)&sProj[id2 * PSTR + jg0 + 4 * q];

        // D = W_hh_tile . h^T + proj   (hi + lo/2048 weight split)
        floatx4 acch, accl;
        acch[0] = prj.x; acch[1] = prj.y; acch[2] = prj.z; acch[3] = prj.w;
        accl[0] = 0.f; accl[1] = 0.f; accl[2] = 0.f; accl[3] = 0.f;
        #pragma unroll
        for (int kc = 0; kc < 4; ++kc) {
            acch = __builtin_amdgcn_mfma_f32_16x16x32_f16(Ah[kc], b[kc], acch, 0, 0, 0);
            accl = __builtin_amdgcn_mfma_f32_16x16x32_f16(Al[kc], b[kc], accl, 0, 0, 0);
        }

        // C layout: lane (n,q) reg i -> h_new[col jg0+4q+i][batch n]
        const bool upd = (t < len_n);
        half4 hsto;
        #pragma unroll
        for (int i = 0; i < 4; ++i) {
            float hv = fast_tanh(acch[i] + accl[i] * (1.0f / 2048.0f));
            hreg[i] = upd ? hv : hreg[i];
            hsto[i] = (_Float16)hreg[i];
        }
        // 4 consecutive cols of one row -> single 8B store
        *(half4*)&hn[n * HSTR + jg0 + 4 * q] = hsto;

        prj = prj2;
        __syncthreads();
    }

    // ---- publish final fp32 h: 4 consecutive cols -> one b128 store
    float4 hf4;
    hf4.x = hreg[0]; hf4.y = hreg[1]; hf4.z = hreg[2]; hf4.w = hreg[3];
    *(float4*)&sHf[n][jg0 + 4 * q] = hf4;
    __syncthreads();

    // ---- epilogue: logits = relu(h) @ W_out^T + b_out, then log_softmax
    for (int it = tid; it < ROWS * On; it += NTHR) {
        int r = it / On, c = it % On;
        float acc = b_out[c];
        for (int k = 0; k < Hn; ++k) {
            float hv = sHf[r][k];
            hv = hv > 0.0f ? hv : 0.0f;
            acc = fmaf(hv, W_out[c * Hn + k], acc);
        }
        sLogit[r][c] = acc;
    }
    __syncthreads();

    if (tid < ROWS) {
        float m = -INFINITY;
        #pragma unroll
        for (int c = 0; c < On; ++c) m = fmaxf(m, sLogit[tid][c]);
        float s = 0.0f;
        #pragma unroll
        for (int c = 0; c < On; ++c) s += __expf(sLogit[tid][c] - m);
        sMLS[tid] = m + __logf(s);
    }
    __syncthreads();

    for (int it = tid; it < ROWS * On; it += NTHR) {
        int r = it / On, c = it % On;
        out[(row0 + r) * On + c] = sLogit[r][c] - sMLS[r];
    }
}

extern "C" void kernel_launch(void* const* d_in, const int* in_sizes, int n_in,
                              void* d_out, int out_size, void* d_ws, size_t ws_size,
                              hipStream_t stream) {
    const int*   x     = (const int*)d_in[0];
    const int*   xlen  = (const int*)d_in[1];
    const float* emb   = (const float*)d_in[2];
    const float* W_ih  = (const float*)d_in[3];
    const float* W_hh  = (const float*)d_in[4];
    const float* b_ih  = (const float*)d_in[5];
    const float* b_hh  = (const float*)d_in[6];
    const float* W_out = (const float*)d_in[7];
    const float* b_out = (const float*)d_in[8];
    float*       out   = (float*)d_out;

    rnn_mfma_kernel<<<NBLK, NTHR, 0, stream>>>(x, xlen, emb, W_ih, W_hh,
                                               b_ih, b_hh, W_out, b_out, out);
}